// Round 1
// baseline (1047.582 us; speedup 1.0000x reference)
//
#include <hip/hip_runtime.h>
#include <math.h>

#define NF 64

// ---------------------------------------------------------------------------
// Kernel 1: scatter-add x[src] rows into agg[dst], and build deg histogram.
// One wave (64 lanes) per edge: lane f handles feature f.
// ---------------------------------------------------------------------------
__global__ __launch_bounds__(256) void k_scatter1(
    const float* __restrict__ x,
    const int* __restrict__ ei,   // [2*E]: src = ei[e], dst = ei[E+e]
    float* __restrict__ agg,
    float* __restrict__ deg,
    int E) {
    int t = blockIdx.x * blockDim.x + threadIdx.x;
    int e = t >> 6;
    if (e >= E) return;
    int f = t & 63;
    int s = ei[e];
    int d = ei[E + e];
    atomicAdd(&agg[(size_t)d * NF + f], x[(size_t)s * NF + f]);
    if (f == 0) atomicAdd(&deg[d], 1.0f);
}

// ---------------------------------------------------------------------------
// Kernel 2: h = (agg/deg) @ Wl1^T + bl1 + x @ Wr1^T   (in-place over agg)
// Also emits p = h @ Wl2^T  ([N,2]) for the cheap layer-2 scatter.
// One wave per node; weights staged transposed in LDS (conflict-free reads).
// ---------------------------------------------------------------------------
__global__ __launch_bounds__(256) void k_layer1(
    const float* __restrict__ x,
    float* __restrict__ agg_h,        // in: agg, out: h
    const float* __restrict__ deg,
    const float* __restrict__ Wl1,
    const float* __restrict__ bl1,
    const float* __restrict__ Wr1,
    const float* __restrict__ Wl2,
    float* __restrict__ p,
    int N) {
    __shared__ float sWl[NF * NF];    // sWl[k*64+o] = Wl1[o*64+k]
    __shared__ float sWr[NF * NF];
    __shared__ float sMean[4][NF];
    __shared__ float sX[4][NF];

    int tid = threadIdx.x;
    // Stage transposed weights: LDS writes coalesced, global reads strided
    // (16 KB matrices, L2 absorbs the strided reads across blocks).
    for (int idx = tid; idx < NF * NF; idx += 256) {
        int k = idx >> 6, o = idx & 63;           // idx = k*64 + o
        sWl[idx] = Wl1[o * NF + k];
        sWr[idx] = Wr1[o * NF + k];
    }

    int w = tid >> 6;                  // wave id within block = local node
    int o = tid & 63;                  // output feature (also input lane)
    int node = blockIdx.x * 4 + w;

    float mean_o = 0.f, x_o = 0.f;
    if (node < N) {
        float dg = deg[node];
        dg = dg > 1.f ? dg : 1.f;
        mean_o = agg_h[(size_t)node * NF + o] / dg;
        x_o = x[(size_t)node * NF + o];
    }
    sMean[w][o] = mean_o;              // within-wave LDS dep: lockstep-safe
    sX[w][o] = x_o;
    __syncthreads();                   // covers the cross-wave weight staging
    if (node >= N) return;

    float acc = bl1[o];
#pragma unroll 8
    for (int k = 0; k < NF; ++k) {
        acc += sMean[w][k] * sWl[k * NF + o];   // broadcast * conflict-free
        acc += sX[w][k] * sWr[k * NF + o];
    }
    agg_h[(size_t)node * NF + o] = acc;         // h row (overwrites agg row)

    // p[node] = h[node] @ Wl2^T  -> 2 scalars via wave butterfly reduce
    float p0 = acc * Wl2[o];
    float p1 = acc * Wl2[NF + o];
    for (int off = 32; off > 0; off >>= 1) {
        p0 += __shfl_down(p0, off, 64);
        p1 += __shfl_down(p1, off, 64);
    }
    if (o == 0) {
        p[(size_t)node * 2 + 0] = p0;
        p[(size_t)node * 2 + 1] = p1;
    }
}

// ---------------------------------------------------------------------------
// Kernel 3: scatter-add p[src] (2 floats) into agg2[dst]. One thread per edge.
// ---------------------------------------------------------------------------
__global__ __launch_bounds__(256) void k_scatter2(
    const float* __restrict__ p,
    const int* __restrict__ ei,
    float* __restrict__ agg2,
    int E) {
    int e = blockIdx.x * blockDim.x + threadIdx.x;
    if (e >= E) return;
    int s = ei[e];
    int d = ei[E + e];
    float2 pv = ((const float2*)p)[s];
    atomicAdd(&agg2[(size_t)d * 2 + 0], pv.x);
    atomicAdd(&agg2[(size_t)d * 2 + 1], pv.y);
}

// ---------------------------------------------------------------------------
// Kernel 4: logits = agg2/deg + bl2 + h @ Wr2^T ; out = log_softmax(logits).
// One wave per node (reduce for the h.Wr2 dots).
// ---------------------------------------------------------------------------
__global__ __launch_bounds__(256) void k_final(
    const float* __restrict__ h,
    const float* __restrict__ agg2,
    const float* __restrict__ deg,
    const float* __restrict__ Wr2,
    const float* __restrict__ bl2,
    float* __restrict__ out,
    int N) {
    int tid = threadIdx.x;
    int w = tid >> 6, f = tid & 63;
    int node = blockIdx.x * 4 + w;
    if (node >= N) return;
    float hv = h[(size_t)node * NF + f];
    float q0 = hv * Wr2[f];
    float q1 = hv * Wr2[NF + f];
    for (int off = 32; off > 0; off >>= 1) {
        q0 += __shfl_down(q0, off, 64);
        q1 += __shfl_down(q1, off, 64);
    }
    if (f == 0) {
        float dg = deg[node];
        dg = dg > 1.f ? dg : 1.f;
        float l0 = agg2[(size_t)node * 2 + 0] / dg + bl2[0] + q0;
        float l1 = agg2[(size_t)node * 2 + 1] / dg + bl2[1] + q1;
        float m = fmaxf(l0, l1);
        float lse = m + logf(expf(l0 - m) + expf(l1 - m));
        out[(size_t)node * 2 + 0] = l0 - lse;
        out[(size_t)node * 2 + 1] = l1 - lse;
    }
}

// ---------------------------------------------------------------------------
extern "C" void kernel_launch(void* const* d_in, const int* in_sizes, int n_in,
                              void* d_out, int out_size, void* d_ws, size_t ws_size,
                              hipStream_t stream) {
    const float* x   = (const float*)d_in[0];
    const int*   ei  = (const int*)d_in[1];
    const float* Wl1 = (const float*)d_in[2];
    const float* bl1 = (const float*)d_in[3];
    const float* Wr1 = (const float*)d_in[4];
    const float* Wl2 = (const float*)d_in[5];
    const float* bl2 = (const float*)d_in[6];
    const float* Wr2 = (const float*)d_in[7];
    float* out = (float*)d_out;

    int N = in_sizes[0] / NF;     // 100000
    int E = in_sizes[1] / 2;      // 1600000

    // Workspace layout (floats): [agg/h: 64N | deg: N | agg2: 2N | p: 2N]
    float* ws    = (float*)d_ws;
    float* agg_h = ws;
    float* deg   = ws + (size_t)64 * N;
    float* agg2  = deg + N;
    float* p     = agg2 + (size_t)2 * N;

    // Zero agg + deg + agg2 (p is fully overwritten).
    hipMemsetAsync(d_ws, 0, (size_t)(64 + 1 + 2) * N * sizeof(float), stream);

    long long t1 = (long long)E * 64;
    k_scatter1<<<(int)((t1 + 255) / 256), 256, 0, stream>>>(x, ei, agg_h, deg, E);
    k_layer1<<<(N + 3) / 4, 256, 0, stream>>>(x, agg_h, deg, Wl1, bl1, Wr1, Wl2, p, N);
    k_scatter2<<<(E + 255) / 256, 256, 0, stream>>>(p, ei, agg2, E);
    k_final<<<(N + 3) / 4, 256, 0, stream>>>(agg_h, agg2, deg, Wr2, bl2, out, N);
}

// Round 3
// 446.158 us; speedup vs baseline: 2.3480x; 2.3480x over previous
//
#include <hip/hip_runtime.h>
#include <math.h>

#define NF 64

// ---------------------------------------------------------------------------
// CSR build: histogram of dst
// ---------------------------------------------------------------------------
__global__ __launch_bounds__(256) void k_hist(
    const int* __restrict__ ei, int* __restrict__ deg, int E) {
    int e = blockIdx.x * 256 + threadIdx.x;
    if (e < E) atomicAdd(&deg[ei[E + e]], 1);
}

// ---------------------------------------------------------------------------
// Exclusive scan, 3 kernels (N <= 512*256)
// ---------------------------------------------------------------------------
__global__ __launch_bounds__(256) void k_scan1(
    const int* __restrict__ deg, int* __restrict__ base,
    int* __restrict__ bsums, int N) {
    __shared__ int s[256];
    int t = threadIdx.x, i = blockIdx.x * 256 + t;
    int v = (i < N) ? deg[i] : 0;
    s[t] = v;
    __syncthreads();
    for (int off = 1; off < 256; off <<= 1) {
        int add = (t >= off) ? s[t - off] : 0;
        __syncthreads();
        s[t] += add;
        __syncthreads();
    }
    if (i < N) base[i] = s[t] - v;           // exclusive within block
    if (t == 255) bsums[blockIdx.x] = s[255];
}

__global__ __launch_bounds__(512) void k_scan2(
    int* __restrict__ bsums, int nb) {
    __shared__ int s[512];
    int t = threadIdx.x;
    int v = (t < nb) ? bsums[t] : 0;
    s[t] = v;
    __syncthreads();
    for (int off = 1; off < 512; off <<= 1) {
        int add = (t >= off) ? s[t - off] : 0;
        __syncthreads();
        s[t] += add;
        __syncthreads();
    }
    if (t < nb) bsums[t] = s[t] - v;         // exclusive
}

__global__ __launch_bounds__(256) void k_scan3(
    int* __restrict__ base, const int* __restrict__ bsums, int N) {
    int i = blockIdx.x * 256 + threadIdx.x;
    if (i < N) base[i] += bsums[blockIdx.x];
}

// ---------------------------------------------------------------------------
// Counting-sort src by dst segment (order within segment irrelevant for sum)
// ---------------------------------------------------------------------------
__global__ __launch_bounds__(256) void k_build(
    const int* __restrict__ ei, const int* __restrict__ base,
    int* __restrict__ cursor, int* __restrict__ sorted, int E) {
    int e = blockIdx.x * 256 + threadIdx.x;
    if (e >= E) return;
    int s = ei[e];
    int d = ei[E + e];
    int pos = atomicAdd(&cursor[d], 1);
    sorted[base[d] + pos] = s;
}

// ---------------------------------------------------------------------------
// Fused layer 1 + projections. One wave per node (grid-stride).
// Weights live in VGPRs (128 regs/lane); activations broadcast via readlane.
// Emits p = h@Wl2^T and q = h@Wr2^T ([N,2] each) so h is never materialized.
// ---------------------------------------------------------------------------
__global__ __launch_bounds__(256, 2) void k_fused1(
    const float* __restrict__ x,
    const int* __restrict__ sorted,
    const int* __restrict__ base,
    const int* __restrict__ deg,
    const float* __restrict__ Wl1,
    const float* __restrict__ bl1,
    const float* __restrict__ Wr1,
    const float* __restrict__ Wl2,
    const float* __restrict__ Wr2,
    float2* __restrict__ p,
    float2* __restrict__ q,
    int N, int nwaves) {
    int tid = blockIdx.x * 256 + threadIdx.x;
    int gw = tid >> 6;      // global wave id
    int lane = tid & 63;

    // Lane o holds row o of Wl1 / Wr1 (contiguous 256 B per lane, L1-cached).
    float wl[NF], wr[NF];
    {
        const float4* wl4 = (const float4*)(Wl1 + (size_t)lane * NF);
        const float4* wr4 = (const float4*)(Wr1 + (size_t)lane * NF);
#pragma unroll
        for (int i = 0; i < NF / 4; ++i) {
            float4 a = wl4[i], b = wr4[i];
            wl[4 * i] = a.x; wl[4 * i + 1] = a.y; wl[4 * i + 2] = a.z; wl[4 * i + 3] = a.w;
            wr[4 * i] = b.x; wr[4 * i + 1] = b.y; wr[4 * i + 2] = b.z; wr[4 * i + 3] = b.w;
        }
    }
    float bl = bl1[lane];
    float wl2a = Wl2[lane], wl2b = Wl2[NF + lane];
    float wr2a = Wr2[lane], wr2b = Wr2[NF + lane];

    for (int node = gw; node < N; node += nwaves) {
        int b0 = base[node];
        int dg = deg[node];

        // Gather-sum x rows of in-neighbors. Neighbor ids loaded 64-wide
        // (coalesced), broadcast via shfl; row reads are coalesced 256 B.
        float sum = 0.f;
        for (int j0 = 0; j0 < dg; j0 += 64) {
            int cnt = dg - j0; if (cnt > 64) cnt = 64;
            int myidx = (lane < cnt) ? sorted[b0 + j0 + lane] : 0;
            int j = 0;
            for (; j + 4 <= cnt; j += 4) {
                int i0 = __shfl(myidx, j, 64);
                int i1 = __shfl(myidx, j + 1, 64);
                int i2 = __shfl(myidx, j + 2, 64);
                int i3 = __shfl(myidx, j + 3, 64);
                sum += x[(size_t)i0 * NF + lane];
                sum += x[(size_t)i1 * NF + lane];
                sum += x[(size_t)i2 * NF + lane];
                sum += x[(size_t)i3 * NF + lane];
            }
            for (; j < cnt; ++j) {
                int i0 = __shfl(myidx, j, 64);
                sum += x[(size_t)i0 * NF + lane];
            }
        }
        float dgf = (float)(dg > 1 ? dg : 1);
        float mean = sum / dgf;                       // lane k holds mean[k]
        float xv = x[(size_t)node * NF + lane];       // lane k holds x[k]

        // h[lane] = bl1[lane] + sum_k mean[k]*Wl1[lane,k] + x[k]*Wr1[lane,k]
        float acc = bl;
#pragma unroll
        for (int k = 0; k < NF; ++k) {
            float mk = __uint_as_float(__builtin_amdgcn_readlane(__float_as_uint(mean), k));
            float xk = __uint_as_float(__builtin_amdgcn_readlane(__float_as_uint(xv), k));
            acc = fmaf(mk, wl[k], acc);
            acc = fmaf(xk, wr[k], acc);
        }

        // p = h @ Wl2^T, q = h @ Wr2^T  (2 scalars each, butterfly reduce)
        float p0 = acc * wl2a, p1 = acc * wl2b;
        float q0 = acc * wr2a, q1 = acc * wr2b;
#pragma unroll
        for (int off = 32; off > 0; off >>= 1) {
            p0 += __shfl_xor(p0, off, 64);
            p1 += __shfl_xor(p1, off, 64);
            q0 += __shfl_xor(q0, off, 64);
            q1 += __shfl_xor(q1, off, 64);
        }
        if (lane == 0) {
            p[node] = make_float2(p0, p1);
            q[node] = make_float2(q0, q1);
        }
    }
}

// ---------------------------------------------------------------------------
// Final: agg2 = gather-sum p over CSR; logits = agg2/deg + bl2 + q;
// out = log_softmax(logits). One wave per node.
// ---------------------------------------------------------------------------
__global__ __launch_bounds__(256) void k_final(
    const float2* __restrict__ p,
    const float2* __restrict__ q,
    const int* __restrict__ sorted,
    const int* __restrict__ base,
    const int* __restrict__ deg,
    const float* __restrict__ bl2,
    float* __restrict__ out,
    int N) {
    int tid = blockIdx.x * 256 + threadIdx.x;
    int node = tid >> 6;
    int lane = tid & 63;
    if (node >= N) return;
    int b0 = base[node];
    int dg = deg[node];
    float s0 = 0.f, s1 = 0.f;
    for (int j = lane; j < dg; j += 64) {
        int idx = sorted[b0 + j];
        float2 pv = p[idx];
        s0 += pv.x; s1 += pv.y;
    }
#pragma unroll
    for (int off = 32; off > 0; off >>= 1) {
        s0 += __shfl_xor(s0, off, 64);
        s1 += __shfl_xor(s1, off, 64);
    }
    if (lane == 0) {
        float dgf = (float)(dg > 1 ? dg : 1);
        float2 qv = q[node];
        float l0 = s0 / dgf + bl2[0] + qv.x;
        float l1 = s1 / dgf + bl2[1] + qv.y;
        float m = fmaxf(l0, l1);
        float lse = m + logf(expf(l0 - m) + expf(l1 - m));
        ((float2*)out)[node] = make_float2(l0 - lse, l1 - lse);
    }
}

// ---------------------------------------------------------------------------
extern "C" void kernel_launch(void* const* d_in, const int* in_sizes, int n_in,
                              void* d_out, int out_size, void* d_ws, size_t ws_size,
                              hipStream_t stream) {
    const float* x   = (const float*)d_in[0];
    const int*   ei  = (const int*)d_in[1];
    const float* Wl1 = (const float*)d_in[2];
    const float* bl1 = (const float*)d_in[3];
    const float* Wr1 = (const float*)d_in[4];
    const float* Wl2 = (const float*)d_in[5];
    const float* bl2 = (const float*)d_in[6];
    const float* Wr2 = (const float*)d_in[7];
    float* out = (float*)d_out;

    int N = in_sizes[0] / NF;     // 100000
    int E = in_sizes[1] / 2;      // 1600000

    // Workspace (ints then floats):
    // [deg:N | cursor:N | base:N | bsums:512 | sorted:E | p:2N f | q:2N f]
    int* wsi    = (int*)d_ws;
    int* deg    = wsi;
    int* cursor = wsi + N;
    int* base   = wsi + 2 * (size_t)N;
    int* bsums  = wsi + 3 * (size_t)N;
    int* sorted = wsi + 3 * (size_t)N + 512;
    float2* p   = (float2*)(wsi + 3 * (size_t)N + 512 + E);
    float2* q   = p + N;

    // Zero deg + cursor (everything else fully overwritten).
    hipMemsetAsync(d_ws, 0, 2 * (size_t)N * sizeof(int), stream);

    int nbE = (E + 255) / 256;
    int nbN = (N + 255) / 256;

    k_hist <<<nbE, 256, 0, stream>>>(ei, deg, E);
    k_scan1<<<nbN, 256, 0, stream>>>(deg, base, bsums, N);
    k_scan2<<<1, 512, 0, stream>>>(bsums, nbN);
    k_scan3<<<nbN, 256, 0, stream>>>(base, bsums, N);
    k_build<<<nbE, 256, 0, stream>>>(ei, base, cursor, sorted, E);

    int blocks1 = 2048;                       // 8192 waves, grid-stride
    int nwaves = blocks1 * 4;
    k_fused1<<<blocks1, 256, 0, stream>>>(x, sorted, base, deg,
                                          Wl1, bl1, Wr1, Wl2, Wr2,
                                          p, q, N, nwaves);
    // One wave per node => N*64 threads total (round-2 bug: was N threads).
    k_final<<<(N * 64 + 255) / 256, 256, 0, stream>>>(p, q, sorted, base, deg,
                                                      bl2, out, N);
}